// Round 6
// baseline (986.820 us; speedup 1.0000x reference)
//
#include <hip/hip_runtime.h>

#define DFEAT 64
typedef unsigned short bf16_t;

typedef __bf16 bf16x8 __attribute__((ext_vector_type(8)));
typedef float f32x4 __attribute__((ext_vector_type(4)));

#define WT_STRIDE 136    // 128 K-elements padded +8 to break LDS bank stride
#define NPB_SHIFT 7      // 128 nodes per bucket
#define NPB 128
#define BCAP 2048        // bucket capacity (mean ~1280 edges, +21 sigma headroom)
#define ATILE 8192       // edges per bucketA block
#define ACC_STRIDE 68    // LDS accumulator row stride (floats), +4 breaks bank stride

__device__ __forceinline__ float bf2f(unsigned short u) {
    union { unsigned int i; float f; } v;
    v.i = ((unsigned int)u) << 16;
    return v.f;
}
__device__ __forceinline__ unsigned short f2bf(float f) {
    unsigned int u = __float_as_uint(f);
    u += 0x7FFFu + ((u >> 16) & 1u);   // round-to-nearest-even
    return (unsigned short)(u >> 16);
}

// ---------------- x -> bf16 cast ----------------
__global__ __launch_bounds__(256) void cast_kernel(const float* __restrict__ x,
                                                   bf16_t* __restrict__ xb, int n_half) {
    int t = blockIdx.x * 256 + threadIdx.x;
    if (t < n_half) {
        float2 v = ((const float2*)x)[t];
        ushort2 o;
        o.x = f2bf(v.x);
        o.y = f2bf(v.y);
        ((ushort2*)xb)[t] = o;
    }
}

// ---------------- W prep: cast to bf16, transpose, concat, pad ----------------
__global__ __launch_bounds__(256) void prep_w(const float* __restrict__ Ws1,
                                              const float* __restrict__ Wn1,
                                              const float* __restrict__ Ws2,
                                              const float* __restrict__ Wn2,
                                              bf16_t* __restrict__ wt1,
                                              bf16_t* __restrict__ wt2) {
    for (int i = threadIdx.x; i < 64 * 128; i += 256) {
        int c = i >> 7;
        int k = i & 127;
        float v1 = (k < 64) ? Ws1[k * 64 + c] : Wn1[(k - 64) * 64 + c];
        float v2 = (k < 64) ? Ws2[k * 64 + c] : Wn2[(k - 64) * 64 + c];
        wt1[c * WT_STRIDE + k] = f2bf(v1);
        wt2[c * WT_STRIDE + k] = f2bf(v2);
    }
}

// ---------------- bucket edges by dst>>7 (packed words) ----------------
// LDS histogram per tile -> one global atomic per bucket per block -> packed
// writes in contiguous runs. pack = (dst&127)<<17 | src  (src < 2^17).
__global__ __launch_bounds__(256) void bucketA(const int* __restrict__ src,
                                               const int* __restrict__ dst,
                                               int* __restrict__ gcur,
                                               int* __restrict__ packbuf,
                                               int n_edges, int nbuck) {
    __shared__ int hist[1024];
    __shared__ int cur[1024];
    const int tid = threadIdx.x;
    const long ebase = (long)blockIdx.x * ATILE;
    for (int i = tid; i < nbuck; i += 256) hist[i] = 0;
    __syncthreads();
    for (int i = 0; i < ATILE / 256; ++i) {
        long e = ebase + i * 256 + tid;
        if (e < n_edges) atomicAdd(&hist[dst[e] >> NPB_SHIFT], 1);
    }
    __syncthreads();
    for (int b = tid; b < nbuck; b += 256) {
        int h = hist[b];
        cur[b] = h ? atomicAdd(&gcur[b], h) : 0;
    }
    __syncthreads();
    for (int i = 0; i < ATILE / 256; ++i) {
        long e = ebase + i * 256 + tid;
        if (e < n_edges) {
            int d = dst[e];
            int b = d >> NPB_SHIFT;
            int slot = atomicAdd(&cur[b], 1);
            if (slot < BCAP)   // safety; never triggers for this distribution
                packbuf[(size_t)b * BCAP + slot] = ((d & (NPB - 1)) << 17) | src[e];
        }
    }
}

// ---------------- fused layer: gather+mean (LDS) then MFMA GEMM --------------
// Block = bucket = 128 consecutive nodes.
// Phase 1: for each bucketed edge, a 16-lane quad gathers the 128 B bf16 src
//   row and ds_add_f32's it into accL[dlocal]; degrees counted in LDS.
// Phase 2: C[128x64] = [x_rows || mean] (K=128 bf16) x W_T, 16x16x32 MFMA.
//   A x-part: direct global 16 B loads; A mean-part: accL * (1/deg) -> bf16.
//   B: ds_read_b128 from wlds (verified layouts from R4 kernel).
__global__ __launch_bounds__(256) void fused_layer(const bf16_t* __restrict__ featb,
                                                   const int* __restrict__ gcur,
                                                   const int* __restrict__ packbuf,
                                                   const bf16_t* __restrict__ wt,
                                                   const float* __restrict__ bias,
                                                   float* __restrict__ outf,
                                                   bf16_t* __restrict__ outb,
                                                   int n_nodes, int do_relu) {
    __shared__ float accL[NPB * ACC_STRIDE];
    __shared__ int   degL[NPB];
    __shared__ bf16_t wlds[64 * WT_STRIDE];

    const int tid = threadIdx.x;
    // stage W_T (17408 B) + zero accumulators
    for (int i = tid; i < (64 * WT_STRIDE * 2) / 16; i += 256)
        ((uint4*)wlds)[i] = ((const uint4*)wt)[i];
    for (int i = tid; i < NPB * ACC_STRIDE; i += 256) accL[i] = 0.0f;
    if (tid < NPB) degL[tid] = 0;
    __syncthreads();

    const int b    = blockIdx.x;
    const int lane = tid & 63;
    const int wave = tid >> 6;
    const int q    = lane >> 4;
    const int cg   = lane & 15;

    // ---- phase 1: edge gather + LDS accumulate ----
    const int count = min(gcur[b], BCAP);
    const int* pb = packbuf + (size_t)b * BCAP;
    for (int i = wave * 4 + q; i < count; i += 32) {
        int pk0 = pb[i];
        int i1  = i + 16;
        bool has1 = i1 < count;
        int pk1 = has1 ? pb[i1] : 0;
        int s0 = pk0 & 0x1FFFF, d0 = (pk0 >> 17) & (NPB - 1);
        int s1 = pk1 & 0x1FFFF, d1 = (pk1 >> 17) & (NPB - 1);
        ushort4 u0 = ((const ushort4*)(featb + (size_t)s0 * DFEAT))[cg];
        ushort4 u1 = has1 ? ((const ushort4*)(featb + (size_t)s1 * DFEAT))[cg]
                          : make_ushort4(0, 0, 0, 0);
        float* a0 = accL + d0 * ACC_STRIDE + cg * 4;
        atomicAdd(a0 + 0, bf2f(u0.x));
        atomicAdd(a0 + 1, bf2f(u0.y));
        atomicAdd(a0 + 2, bf2f(u0.z));
        atomicAdd(a0 + 3, bf2f(u0.w));
        if (cg == 0) atomicAdd(&degL[d0], 1);
        if (has1) {
            float* a1 = accL + d1 * ACC_STRIDE + cg * 4;
            atomicAdd(a1 + 0, bf2f(u1.x));
            atomicAdd(a1 + 1, bf2f(u1.y));
            atomicAdd(a1 + 2, bf2f(u1.z));
            atomicAdd(a1 + 3, bf2f(u1.w));
            if (cg == 0) atomicAdd(&degL[d1], 1);
        }
    }
    __syncthreads();

    // ---- phase 2: MFMA GEMM for this bucket's 128 nodes ----
    const int nodeBase = b << NPB_SHIFT;
    f32x4 acc[2][4] = {};

#pragma unroll
    for (int slab = 0; slab < 2; ++slab) {
        const int r = wave * 32 + slab * 16 + cg;   // row within block (< 128)
        int nodeA = nodeBase + r;
        if (nodeA >= n_nodes) nodeA = n_nodes - 1;  // clamp; stores predicated

        const bf16_t* xrow = featb + (size_t)nodeA * DFEAT + q * 8;
        bf16x8 a0 = *(const bf16x8*)(xrow);
        bf16x8 a1 = *(const bf16x8*)(xrow + 32);

        int dg = degL[r];
        float inv = (dg > 0) ? 1.0f / (float)dg : 0.0f;
        const float* arow = accL + r * ACC_STRIDE + q * 8;
        union { unsigned short u[8]; bf16x8 v; } A2, A3;
#pragma unroll
        for (int j = 0; j < 8; ++j) {
            A2.u[j] = f2bf(arow[j] * inv);
            A3.u[j] = f2bf(arow[32 + j] * inv);
        }

#pragma unroll
        for (int nt = 0; nt < 4; ++nt) {
            const bf16_t* wb = wlds + (size_t)(nt * 16 + cg) * WT_STRIDE + q * 8;
            acc[slab][nt] = __builtin_amdgcn_mfma_f32_16x16x32_bf16(
                a0, *(const bf16x8*)(wb), acc[slab][nt], 0, 0, 0);
            acc[slab][nt] = __builtin_amdgcn_mfma_f32_16x16x32_bf16(
                a1, *(const bf16x8*)(wb + 32), acc[slab][nt], 0, 0, 0);
            acc[slab][nt] = __builtin_amdgcn_mfma_f32_16x16x32_bf16(
                A2.v, *(const bf16x8*)(wb + 64), acc[slab][nt], 0, 0, 0);
            acc[slab][nt] = __builtin_amdgcn_mfma_f32_16x16x32_bf16(
                A3.v, *(const bf16x8*)(wb + 96), acc[slab][nt], 0, 0, 0);
        }
    }

    // epilogue: D row = q*4 + reg (within 16-tile), col = nt*16 + cg
#pragma unroll
    for (int slab = 0; slab < 2; ++slab) {
#pragma unroll
        for (int nt = 0; nt < 4; ++nt) {
            const float bl = bias[nt * 16 + cg];
#pragma unroll
            for (int reg = 0; reg < 4; ++reg) {
                int node = nodeBase + wave * 32 + slab * 16 + q * 4 + reg;
                if (node >= n_nodes) continue;
                float v = acc[slab][nt][reg] + bl;
                if (do_relu) v = fmaxf(v, 0.0f);
                if (outf) outf[(size_t)node * DFEAT + nt * 16 + cg] = v;
                else      outb[(size_t)node * DFEAT + nt * 16 + cg] = f2bf(v);
            }
        }
    }
}

// -------------------------------------------------------------------------

extern "C" void kernel_launch(void* const* d_in, const int* in_sizes, int n_in,
                              void* d_out, int out_size, void* d_ws, size_t ws_size,
                              hipStream_t stream) {
    const float* x       = (const float*)d_in[0];
    const int*   src     = (const int*)d_in[1];
    const int*   dst     = (const int*)d_in[2];
    const float* Wself1  = (const float*)d_in[3];
    const float* Wneigh1 = (const float*)d_in[4];
    const float* b1      = (const float*)d_in[5];
    const float* Wself2  = (const float*)d_in[6];
    const float* Wneigh2 = (const float*)d_in[7];
    const float* b2      = (const float*)d_in[8];
    float* out = (float*)d_out;

    const int n_nodes = in_sizes[0] / DFEAT;
    const int n_edges = in_sizes[1];
    const int nbuck   = (n_nodes + NPB - 1) >> NPB_SHIFT;   // 782

    // Workspace: gcur[1024] | wt1 | wt2 | packbuf[nbuck*BCAP] | xb[N*D] | hb[N*D]
    int* gcur       = (int*)d_ws;
    bf16_t* wt1     = (bf16_t*)(gcur + 1024);
    bf16_t* wt2     = wt1 + 64 * WT_STRIDE;
    int* packbuf    = (int*)(wt2 + 64 * WT_STRIDE);
    bf16_t* xb      = (bf16_t*)(packbuf + (size_t)nbuck * BCAP);
    bf16_t* hb      = xb + (size_t)n_nodes * DFEAT;

    const int n_half = n_nodes * DFEAT / 2;
    const int cb = (n_half + 255) / 256;
    const int ab = (n_edges + ATILE - 1) / ATILE;

    hipMemsetAsync(gcur, 0, 1024 * sizeof(int), stream);
    cast_kernel<<<cb, 256, 0, stream>>>(x, xb, n_half);
    prep_w<<<1, 256, 0, stream>>>(Wself1, Wneigh1, Wself2, Wneigh2, wt1, wt2);
    bucketA<<<ab, 256, 0, stream>>>(src, dst, gcur, packbuf, n_edges, nbuck);

    fused_layer<<<nbuck, 256, 0, stream>>>(xb, gcur, packbuf, wt1, b1,
                                           nullptr, hb, n_nodes, 1);
    fused_layer<<<nbuck, 256, 0, stream>>>(hb, gcur, packbuf, wt2, b2,
                                           out, nullptr, n_nodes, 0);
}

// Round 7
// 261.508 us; speedup vs baseline: 3.7736x; 3.7736x over previous
//
#include <hip/hip_runtime.h>

#define DFEAT 64
typedef unsigned short bf16_t;

typedef __bf16 bf16x8 __attribute__((ext_vector_type(8)));
typedef float f32x4 __attribute__((ext_vector_type(4)));

#define WT_STRIDE 136    // 128 K-elements padded +8 to break LDS bank stride
#define NPB_SHIFT 7      // 128 nodes per bucket
#define NPB 128
#define BCAP 2048        // bucket capacity (mean ~1280 edges, +21 sigma headroom)
#define ATILE 8192       // edges per bucketA block
#define MEAN_STRIDE 72   // LDS mean row stride in bf16 (144 B, 16B-aligned, +8 pad)

__device__ __forceinline__ float bf2f(unsigned short u) {
    union { unsigned int i; float f; } v;
    v.i = ((unsigned int)u) << 16;
    return v.f;
}
__device__ __forceinline__ unsigned short f2bf(float f) {
    unsigned int u = __float_as_uint(f);
    u += 0x7FFFu + ((u >> 16) & 1u);   // round-to-nearest-even
    return (unsigned short)(u >> 16);
}

// ---------------- x -> bf16 cast ----------------
__global__ __launch_bounds__(256) void cast_kernel(const float* __restrict__ x,
                                                   bf16_t* __restrict__ xb, int n_half) {
    int t = blockIdx.x * 256 + threadIdx.x;
    if (t < n_half) {
        float2 v = ((const float2*)x)[t];
        ushort2 o;
        o.x = f2bf(v.x);
        o.y = f2bf(v.y);
        ((ushort2*)xb)[t] = o;
    }
}

// ---------------- W prep: cast to bf16, transpose, concat, pad ----------------
__global__ __launch_bounds__(256) void prep_w(const float* __restrict__ Ws1,
                                              const float* __restrict__ Wn1,
                                              const float* __restrict__ Ws2,
                                              const float* __restrict__ Wn2,
                                              bf16_t* __restrict__ wt1,
                                              bf16_t* __restrict__ wt2) {
    for (int i = threadIdx.x; i < 64 * 128; i += 256) {
        int c = i >> 7;
        int k = i & 127;
        float v1 = (k < 64) ? Ws1[k * 64 + c] : Wn1[(k - 64) * 64 + c];
        float v2 = (k < 64) ? Ws2[k * 64 + c] : Wn2[(k - 64) * 64 + c];
        wt1[c * WT_STRIDE + k] = f2bf(v1);
        wt2[c * WT_STRIDE + k] = f2bf(v2);
    }
}

// ---------------- bucket edges by dst>>7 (packed words) ----------------
// pack = (dst&127)<<17 | src  (src < 2^17).
__global__ __launch_bounds__(256) void bucketA(const int* __restrict__ src,
                                               const int* __restrict__ dst,
                                               int* __restrict__ gcur,
                                               int* __restrict__ packbuf,
                                               int n_edges, int nbuck) {
    __shared__ int hist[1024];
    __shared__ int cur[1024];
    const int tid = threadIdx.x;
    const long ebase = (long)blockIdx.x * ATILE;
    for (int i = tid; i < nbuck; i += 256) hist[i] = 0;
    __syncthreads();
    for (int i = 0; i < ATILE / 256; ++i) {
        long e = ebase + i * 256 + tid;
        if (e < n_edges) atomicAdd(&hist[dst[e] >> NPB_SHIFT], 1);
    }
    __syncthreads();
    for (int b = tid; b < nbuck; b += 256) {
        int h = hist[b];
        cur[b] = h ? atomicAdd(&gcur[b], h) : 0;
    }
    __syncthreads();
    for (int i = 0; i < ATILE / 256; ++i) {
        long e = ebase + i * 256 + tid;
        if (e < n_edges) {
            int d = dst[e];
            int b = d >> NPB_SHIFT;
            int slot = atomicAdd(&cur[b], 1);
            if (slot < BCAP)   // safety; never triggers for this distribution
                packbuf[(size_t)b * BCAP + slot] = ((d & (NPB - 1)) << 17) | src[e];
        }
    }
}

// ---------------- fused layer: LDS counting-sort -> register gather -> MFMA --
// Block = bucket = 128 consecutive nodes. NO float atomics:
//   P1 LDS int histogram of dlocal (edges cached in registers, 8/thread)
//   P2 128-wide exclusive scan
//   P3 scatter src ids into per-node-contiguous LDS elist
//   P4 quad (16 lanes) owns 8 nodes; walks each node's LDS edge list
//      (broadcast reads), gathers 128 B rows 4-deep, accumulates in REGISTERS,
//      writes bf16 mean to padded LDS tile
//   P5 MFMA GEMM: A = [x-row (global) || mean (LDS)], B = W_T (LDS)
__global__ __launch_bounds__(256) void fused_layer(const bf16_t* __restrict__ featb,
                                                   const int* __restrict__ gcur,
                                                   const int* __restrict__ packbuf,
                                                   const bf16_t* __restrict__ wt,
                                                   const float* __restrict__ bias,
                                                   float* __restrict__ outf,
                                                   bf16_t* __restrict__ outb,
                                                   int n_nodes, int do_relu) {
    __shared__ bf16_t wlds[64 * WT_STRIDE];          // 17408 B
    __shared__ int    elist[BCAP];                   //  8192 B
    __shared__ bf16_t meanL[NPB * MEAN_STRIDE];      // 18432 B
    __shared__ int    hist[NPB];
    __shared__ int    scanb[NPB];
    __shared__ int    cur[NPB];

    const int tid = threadIdx.x;
    const int b   = blockIdx.x;

    // stage W_T + zero histogram
    for (int i = tid; i < (64 * WT_STRIDE * 2) / 16; i += 256)
        ((uint4*)wlds)[i] = ((const uint4*)wt)[i];
    if (tid < NPB) hist[tid] = 0;
    __syncthreads();

    const int count = min(gcur[b], BCAP);
    const int* pb = packbuf + (size_t)b * BCAP;

    // ---- P1: cache edges in registers + LDS int histogram ----
    int pkreg[BCAP / 256];
#pragma unroll
    for (int k = 0; k < BCAP / 256; ++k) {
        int i = tid + k * 256;
        if (i < count) {
            int pk = pb[i];
            pkreg[k] = pk;
            atomicAdd(&hist[(pk >> 17) & (NPB - 1)], 1);
        }
    }
    __syncthreads();

    // ---- P2: exclusive scan over 128 counters (Hillis-Steele) ----
    int hv = (tid < NPB) ? hist[tid] : 0;
    if (tid < NPB) scanb[tid] = hv;
    __syncthreads();
    for (int off = 1; off < NPB; off <<= 1) {
        int t = 0;
        if (tid < NPB && tid >= off) t = scanb[tid - off];
        __syncthreads();
        if (tid < NPB) scanb[tid] += t;
        __syncthreads();
    }
    if (tid < NPB) {
        int ex = scanb[tid] - hv;
        scanb[tid] = ex;
        cur[tid]   = ex;
    }
    __syncthreads();

    // ---- P3: scatter src ids into per-node-contiguous LDS list ----
#pragma unroll
    for (int k = 0; k < BCAP / 256; ++k) {
        int i = tid + k * 256;
        if (i < count) {
            int pk = pkreg[k];
            int dl = (pk >> 17) & (NPB - 1);
            int pos = atomicAdd(&cur[dl], 1);
            elist[pos] = pk & 0x1FFFF;
        }
    }
    __syncthreads();

    // ---- P4: owner-computes gather + mean (registers only) ----
    const int qg = tid >> 4;        // quad 0..15
    const int cg = tid & 15;        // lane within quad
    for (int n = 0; n < NPB / 16; ++n) {
        int r  = qg * (NPB / 16) + n;
        int s0 = scanb[r];
        int c  = hist[r];
        float4 sum = make_float4(0.f, 0.f, 0.f, 0.f);
        int i = 0;
        for (; i + 4 <= c; i += 4) {
            int e0 = elist[s0 + i + 0];
            int e1 = elist[s0 + i + 1];
            int e2 = elist[s0 + i + 2];
            int e3 = elist[s0 + i + 3];
            ushort4 u0 = ((const ushort4*)(featb + (size_t)e0 * DFEAT))[cg];
            ushort4 u1 = ((const ushort4*)(featb + (size_t)e1 * DFEAT))[cg];
            ushort4 u2 = ((const ushort4*)(featb + (size_t)e2 * DFEAT))[cg];
            ushort4 u3 = ((const ushort4*)(featb + (size_t)e3 * DFEAT))[cg];
            sum.x += bf2f(u0.x) + bf2f(u1.x) + bf2f(u2.x) + bf2f(u3.x);
            sum.y += bf2f(u0.y) + bf2f(u1.y) + bf2f(u2.y) + bf2f(u3.y);
            sum.z += bf2f(u0.z) + bf2f(u1.z) + bf2f(u2.z) + bf2f(u3.z);
            sum.w += bf2f(u0.w) + bf2f(u1.w) + bf2f(u2.w) + bf2f(u3.w);
        }
        for (; i < c; ++i) {
            int e0 = elist[s0 + i];
            ushort4 u = ((const ushort4*)(featb + (size_t)e0 * DFEAT))[cg];
            sum.x += bf2f(u.x); sum.y += bf2f(u.y);
            sum.z += bf2f(u.z); sum.w += bf2f(u.w);
        }
        float inv = (c > 0) ? 1.0f / (float)c : 0.0f;
        ushort4 o;
        o.x = f2bf(sum.x * inv);
        o.y = f2bf(sum.y * inv);
        o.z = f2bf(sum.z * inv);
        o.w = f2bf(sum.w * inv);
        *(ushort4*)(meanL + (size_t)r * MEAN_STRIDE + cg * 4) = o;
    }
    __syncthreads();

    // ---- P5: MFMA GEMM for this bucket's 128 nodes ----
    const int lane = tid & 63;
    const int wave = tid >> 6;
    const int q    = lane >> 4;
    const int cgl  = lane & 15;
    const int nodeBase = b << NPB_SHIFT;

    f32x4 acc[2][4] = {};
#pragma unroll
    for (int slab = 0; slab < 2; ++slab) {
        const int r = wave * 32 + slab * 16 + cgl;   // row within bucket
        int nodeA = nodeBase + r;
        if (nodeA >= n_nodes) nodeA = n_nodes - 1;   // clamp; stores predicated

        const bf16_t* xrow = featb + (size_t)nodeA * DFEAT + q * 8;
        bf16x8 a0 = *(const bf16x8*)(xrow);
        bf16x8 a1 = *(const bf16x8*)(xrow + 32);
        const bf16_t* mrow = meanL + (size_t)r * MEAN_STRIDE + q * 8;
        bf16x8 a2 = *(const bf16x8*)(mrow);
        bf16x8 a3 = *(const bf16x8*)(mrow + 32);

#pragma unroll
        for (int nt = 0; nt < 4; ++nt) {
            const bf16_t* wb = wlds + (size_t)(nt * 16 + cgl) * WT_STRIDE + q * 8;
            acc[slab][nt] = __builtin_amdgcn_mfma_f32_16x16x32_bf16(
                a0, *(const bf16x8*)(wb), acc[slab][nt], 0, 0, 0);
            acc[slab][nt] = __builtin_amdgcn_mfma_f32_16x16x32_bf16(
                a1, *(const bf16x8*)(wb + 32), acc[slab][nt], 0, 0, 0);
            acc[slab][nt] = __builtin_amdgcn_mfma_f32_16x16x32_bf16(
                a2, *(const bf16x8*)(wb + 64), acc[slab][nt], 0, 0, 0);
            acc[slab][nt] = __builtin_amdgcn_mfma_f32_16x16x32_bf16(
                a3, *(const bf16x8*)(wb + 96), acc[slab][nt], 0, 0, 0);
        }
    }

    // epilogue: D row = q*4 + reg (within 16-tile), col = nt*16 + cgl
#pragma unroll
    for (int slab = 0; slab < 2; ++slab) {
#pragma unroll
        for (int nt = 0; nt < 4; ++nt) {
            const float bl = bias[nt * 16 + cgl];
#pragma unroll
            for (int reg = 0; reg < 4; ++reg) {
                int node = nodeBase + wave * 32 + slab * 16 + q * 4 + reg;
                if (node >= n_nodes) continue;
                float v = acc[slab][nt][reg] + bl;
                if (do_relu) v = fmaxf(v, 0.0f);
                if (outf) outf[(size_t)node * DFEAT + nt * 16 + cgl] = v;
                else      outb[(size_t)node * DFEAT + nt * 16 + cgl] = f2bf(v);
            }
        }
    }
}

// -------------------------------------------------------------------------

extern "C" void kernel_launch(void* const* d_in, const int* in_sizes, int n_in,
                              void* d_out, int out_size, void* d_ws, size_t ws_size,
                              hipStream_t stream) {
    const float* x       = (const float*)d_in[0];
    const int*   src     = (const int*)d_in[1];
    const int*   dst     = (const int*)d_in[2];
    const float* Wself1  = (const float*)d_in[3];
    const float* Wneigh1 = (const float*)d_in[4];
    const float* b1      = (const float*)d_in[5];
    const float* Wself2  = (const float*)d_in[6];
    const float* Wneigh2 = (const float*)d_in[7];
    const float* b2      = (const float*)d_in[8];
    float* out = (float*)d_out;

    const int n_nodes = in_sizes[0] / DFEAT;
    const int n_edges = in_sizes[1];
    const int nbuck   = (n_nodes + NPB - 1) >> NPB_SHIFT;   // 782

    // Workspace: gcur[1024] | wt1 | wt2 | packbuf[nbuck*BCAP] | xb[N*D] | hb[N*D]
    int* gcur       = (int*)d_ws;
    bf16_t* wt1     = (bf16_t*)(gcur + 1024);
    bf16_t* wt2     = wt1 + 64 * WT_STRIDE;
    int* packbuf    = (int*)(wt2 + 64 * WT_STRIDE);
    bf16_t* xb      = (bf16_t*)(packbuf + (size_t)nbuck * BCAP);
    bf16_t* hb      = xb + (size_t)n_nodes * DFEAT;

    const int n_half = n_nodes * DFEAT / 2;
    const int cb = (n_half + 255) / 256;
    const int ab = (n_edges + ATILE - 1) / ATILE;

    hipMemsetAsync(gcur, 0, 1024 * sizeof(int), stream);
    cast_kernel<<<cb, 256, 0, stream>>>(x, xb, n_half);
    prep_w<<<1, 256, 0, stream>>>(Wself1, Wneigh1, Wself2, Wneigh2, wt1, wt2);
    bucketA<<<ab, 256, 0, stream>>>(src, dst, gcur, packbuf, n_edges, nbuck);

    fused_layer<<<nbuck, 256, 0, stream>>>(xb, gcur, packbuf, wt1, b1,
                                           nullptr, hb, n_nodes, 1);
    fused_layer<<<nbuck, 256, 0, stream>>>(hb, gcur, packbuf, wt2, b2,
                                           out, nullptr, n_nodes, 0);
}

// Round 8
// 186.673 us; speedup vs baseline: 5.2864x; 1.4009x over previous
//
#include <hip/hip_runtime.h>

#define DFEAT 64
typedef unsigned short bf16_t;

typedef __bf16 bf16x8 __attribute__((ext_vector_type(8)));
typedef float f32x4 __attribute__((ext_vector_type(4)));

#define NPB_SHIFT 7      // 128 nodes per bucket
#define NPB 128
#define BCAP 2048        // bucket capacity (mean ~1280 edges, +21 sigma headroom)
#define ATILE 8192       // edges per bucketing block
#define MEAN_STRIDE 72   // LDS mean row stride in bf16 (144 B: 16B-aligned, breaks bank stride)

__device__ __forceinline__ float bf2f(unsigned short u) {
    union { unsigned int i; float f; } v;
    v.i = ((unsigned int)u) << 16;
    return v.f;
}
__device__ __forceinline__ float bflo(unsigned int u) {   // low bf16 of packed word
    union { unsigned int i; float f; } v;
    v.i = u << 16;
    return v.f;
}
__device__ __forceinline__ float bfhi(unsigned int u) {   // high bf16 of packed word
    union { unsigned int i; float f; } v;
    v.i = u & 0xFFFF0000u;
    return v.f;
}
__device__ __forceinline__ unsigned short f2bf(float f) {
    unsigned int u = __float_as_uint(f);
    u += 0x7FFFu + ((u >> 16) & 1u);   // round-to-nearest-even
    return (unsigned short)(u >> 16);
}

// ---------------- fused prep: bucketing | x->bf16 cast | W frag-major --------
// blocks [0, ab)        : bucket edges by dst>>7, pack = (dst&127)<<17 | src
// blocks [ab, ab+cb)    : cast x to bf16
// block  ab+cb          : W -> bf16 fragment-major for direct per-lane loads
__global__ __launch_bounds__(256) void prep_all(const int* __restrict__ src,
                                                const int* __restrict__ dst,
                                                int* __restrict__ gcur,
                                                int* __restrict__ packbuf,
                                                int n_edges, int nbuck,
                                                const float* __restrict__ x,
                                                bf16_t* __restrict__ xb, int n_half,
                                                const float* __restrict__ Ws1,
                                                const float* __restrict__ Wn1,
                                                const float* __restrict__ Ws2,
                                                const float* __restrict__ Wn2,
                                                bf16_t* __restrict__ wf1,
                                                bf16_t* __restrict__ wf2,
                                                int ab, int cb) {
    const int tid = threadIdx.x;
    const int blk = blockIdx.x;
    if (blk < ab) {
        __shared__ int hist[1024];
        __shared__ int cur[1024];
        const long ebase = (long)blk * ATILE;
        for (int i = tid; i < nbuck; i += 256) hist[i] = 0;
        __syncthreads();
        for (int i = 0; i < ATILE / 256; ++i) {
            long e = ebase + i * 256 + tid;
            if (e < n_edges) atomicAdd(&hist[dst[e] >> NPB_SHIFT], 1);
        }
        __syncthreads();
        for (int b = tid; b < nbuck; b += 256) {
            int h = hist[b];
            cur[b] = h ? atomicAdd(&gcur[b], h) : 0;
        }
        __syncthreads();
        for (int i = 0; i < ATILE / 256; ++i) {
            long e = ebase + i * 256 + tid;
            if (e < n_edges) {
                int d = dst[e];
                int b = d >> NPB_SHIFT;
                int slot = atomicAdd(&cur[b], 1);
                if (slot < BCAP)   // safety; never triggers for this distribution
                    packbuf[(size_t)b * BCAP + slot] = ((d & (NPB - 1)) << 17) | src[e];
            }
        }
    } else if (blk < ab + cb) {
        int t = (blk - ab) * 256 + tid;
        if (t < n_half) {
            float2 v = ((const float2*)x)[t];
            ushort2 o;
            o.x = f2bf(v.x);
            o.y = f2bf(v.y);
            ((ushort2*)xb)[t] = o;
        }
    } else {
        // fragment-major W: wf[(f*64 + l)*8 + j], f = kk*4+nt,
        // k = kk*32 + (l>>4)*8 + j, col = nt*16 + (l&15)
        for (int i = tid; i < 16 * 64 * 8; i += 256) {
            int j = i & 7;
            int l = (i >> 3) & 63;
            int f = i >> 9;
            int kk = f >> 2, nt = f & 3;
            int k = kk * 32 + (l >> 4) * 8 + j;
            int col = nt * 16 + (l & 15);
            float v1 = (k < 64) ? Ws1[k * 64 + col] : Wn1[(k - 64) * 64 + col];
            float v2 = (k < 64) ? Ws2[k * 64 + col] : Wn2[(k - 64) * 64 + col];
            wf1[i] = f2bf(v1);
            wf2[i] = f2bf(v2);
        }
    }
}

// ---------------- fused layer: LDS counting-sort -> oct gather -> MFMA -------
// Block = bucket = 128 consecutive nodes. LDS = 28 KB (no W staging).
//   P1 edges cached in registers + LDS int histogram of dlocal
//   P2 128-wide exclusive scan
//   P3 scatter src ids into per-node-contiguous LDS elist
//   P4 oct (8 lanes) owns 4 nodes; walks each node's LDS edge list, gathers
//      128 B rows as ushort8/lane, 4-deep unroll (32 x 16 B in flight / wave),
//      accumulates in registers, writes bf16 mean to padded LDS tile
//   P5 MFMA: A = [x-row (global) || mean (LDS)], B = per-lane frags from
//      global wf (L1-resident 16 KB)
__global__ __launch_bounds__(256) void fused_layer(const bf16_t* __restrict__ featb,
                                                   const int* __restrict__ gcur,
                                                   const int* __restrict__ packbuf,
                                                   const bf16_t* __restrict__ wf,
                                                   const float* __restrict__ bias,
                                                   float* __restrict__ outf,
                                                   bf16_t* __restrict__ outb,
                                                   int n_nodes, int do_relu) {
    __shared__ int    elist[BCAP];                   //  8192 B
    __shared__ bf16_t meanL[NPB * MEAN_STRIDE];      // 18432 B
    __shared__ int    hist[NPB];
    __shared__ int    scanb[NPB];
    __shared__ int    cur[NPB];

    const int tid = threadIdx.x;
    const int b   = blockIdx.x;

    if (tid < NPB) hist[tid] = 0;
    __syncthreads();

    const int count = min(gcur[b], BCAP);
    const int* pb = packbuf + (size_t)b * BCAP;

    // ---- P1: cache edges in registers + LDS int histogram ----
    int pkreg[BCAP / 256];
#pragma unroll
    for (int k = 0; k < BCAP / 256; ++k) {
        int i = tid + k * 256;
        if (i < count) {
            int pk = pb[i];
            pkreg[k] = pk;
            atomicAdd(&hist[(pk >> 17) & (NPB - 1)], 1);
        }
    }
    __syncthreads();

    // ---- P2: exclusive scan over 128 counters ----
    int hv = (tid < NPB) ? hist[tid] : 0;
    if (tid < NPB) scanb[tid] = hv;
    __syncthreads();
    for (int off = 1; off < NPB; off <<= 1) {
        int t = 0;
        if (tid < NPB && tid >= off) t = scanb[tid - off];
        __syncthreads();
        if (tid < NPB) scanb[tid] += t;
        __syncthreads();
    }
    if (tid < NPB) {
        int ex = scanb[tid] - hv;
        scanb[tid] = ex;
        cur[tid]   = ex;
    }
    __syncthreads();

    // ---- P3: scatter src ids into per-node-contiguous LDS list ----
#pragma unroll
    for (int k = 0; k < BCAP / 256; ++k) {
        int i = tid + k * 256;
        if (i < count) {
            int pk = pkreg[k];
            int dl = (pk >> 17) & (NPB - 1);
            int pos = atomicAdd(&cur[dl], 1);
            elist[pos] = pk & 0x1FFFF;
        }
    }
    __syncthreads();

    // ---- P4: oct-owner gather, 16 B/lane, 4-deep ----
    const int oct = tid >> 3;       // 0..31
    const int lo  = tid & 7;        // lane in oct; owns cols lo*8 .. lo*8+7
#pragma unroll
    for (int n = 0; n < 4; ++n) {
        int r  = oct * 4 + n;
        int s0 = scanb[r];
        int c  = hist[r];
        float s0f = 0.f, s1f = 0.f, s2f = 0.f, s3f = 0.f;
        float s4f = 0.f, s5f = 0.f, s6f = 0.f, s7f = 0.f;
        int i = 0;
        for (; i + 4 <= c; i += 4) {
            int e0 = elist[s0 + i + 0];
            int e1 = elist[s0 + i + 1];
            int e2 = elist[s0 + i + 2];
            int e3 = elist[s0 + i + 3];
            uint4 u0 = *(const uint4*)(featb + (size_t)e0 * DFEAT + lo * 8);
            uint4 u1 = *(const uint4*)(featb + (size_t)e1 * DFEAT + lo * 8);
            uint4 u2 = *(const uint4*)(featb + (size_t)e2 * DFEAT + lo * 8);
            uint4 u3 = *(const uint4*)(featb + (size_t)e3 * DFEAT + lo * 8);
            s0f += bflo(u0.x) + bflo(u1.x) + bflo(u2.x) + bflo(u3.x);
            s1f += bfhi(u0.x) + bfhi(u1.x) + bfhi(u2.x) + bfhi(u3.x);
            s2f += bflo(u0.y) + bflo(u1.y) + bflo(u2.y) + bflo(u3.y);
            s3f += bfhi(u0.y) + bfhi(u1.y) + bfhi(u2.y) + bfhi(u3.y);
            s4f += bflo(u0.z) + bflo(u1.z) + bflo(u2.z) + bflo(u3.z);
            s5f += bfhi(u0.z) + bfhi(u1.z) + bfhi(u2.z) + bfhi(u3.z);
            s6f += bflo(u0.w) + bflo(u1.w) + bflo(u2.w) + bflo(u3.w);
            s7f += bfhi(u0.w) + bfhi(u1.w) + bfhi(u2.w) + bfhi(u3.w);
        }
        for (; i < c; ++i) {
            int e0 = elist[s0 + i];
            uint4 u = *(const uint4*)(featb + (size_t)e0 * DFEAT + lo * 8);
            s0f += bflo(u.x); s1f += bfhi(u.x);
            s2f += bflo(u.y); s3f += bfhi(u.y);
            s4f += bflo(u.z); s5f += bfhi(u.z);
            s6f += bflo(u.w); s7f += bfhi(u.w);
        }
        float inv = (c > 0) ? 1.0f / (float)c : 0.0f;
        uint4 o;
        o.x = (unsigned int)f2bf(s0f * inv) | ((unsigned int)f2bf(s1f * inv) << 16);
        o.y = (unsigned int)f2bf(s2f * inv) | ((unsigned int)f2bf(s3f * inv) << 16);
        o.z = (unsigned int)f2bf(s4f * inv) | ((unsigned int)f2bf(s5f * inv) << 16);
        o.w = (unsigned int)f2bf(s6f * inv) | ((unsigned int)f2bf(s7f * inv) << 16);
        *(uint4*)(meanL + (size_t)r * MEAN_STRIDE + lo * 8) = o;
    }
    __syncthreads();

    // ---- P5: MFMA GEMM, B-fragments direct from global (L1-hot) ----
    const int lane = tid & 63;
    const int wave = tid >> 6;
    const int q    = lane >> 4;
    const int cgl  = lane & 15;
    const int nodeBase = b << NPB_SHIFT;

    bf16x8 a[2][4];
#pragma unroll
    for (int slab = 0; slab < 2; ++slab) {
        const int r = wave * 32 + slab * 16 + cgl;
        int nodeA = nodeBase + r;
        if (nodeA >= n_nodes) nodeA = n_nodes - 1;   // clamp; stores predicated
        const bf16_t* xrow = featb + (size_t)nodeA * DFEAT + q * 8;
        a[slab][0] = *(const bf16x8*)(xrow);
        a[slab][1] = *(const bf16x8*)(xrow + 32);
        const bf16_t* mrow = meanL + (size_t)r * MEAN_STRIDE + q * 8;
        a[slab][2] = *(const bf16x8*)(mrow);
        a[slab][3] = *(const bf16x8*)(mrow + 32);
    }

    f32x4 acc[2][4] = {};
#pragma unroll
    for (int nt = 0; nt < 4; ++nt) {
        bf16x8 bf[4];
#pragma unroll
        for (int kk = 0; kk < 4; ++kk)
            bf[kk] = *(const bf16x8*)(wf + (size_t)((kk * 4 + nt) * 64 + lane) * 8);
#pragma unroll
        for (int slab = 0; slab < 2; ++slab) {
#pragma unroll
            for (int kk = 0; kk < 4; ++kk)
                acc[slab][nt] = __builtin_amdgcn_mfma_f32_16x16x32_bf16(
                    a[slab][kk], bf[kk], acc[slab][nt], 0, 0, 0);
        }
    }

    // epilogue: D row = q*4 + reg (within 16-tile), col = nt*16 + cgl
#pragma unroll
    for (int slab = 0; slab < 2; ++slab) {
#pragma unroll
        for (int nt = 0; nt < 4; ++nt) {
            const float bl = bias[nt * 16 + cgl];
#pragma unroll
            for (int reg = 0; reg < 4; ++reg) {
                int node = nodeBase + wave * 32 + slab * 16 + q * 4 + reg;
                if (node >= n_nodes) continue;
                float v = acc[slab][nt][reg] + bl;
                if (do_relu) v = fmaxf(v, 0.0f);
                if (outf) outf[(size_t)node * DFEAT + nt * 16 + cgl] = v;
                else      outb[(size_t)node * DFEAT + nt * 16 + cgl] = f2bf(v);
            }
        }
    }
}

// -------------------------------------------------------------------------

extern "C" void kernel_launch(void* const* d_in, const int* in_sizes, int n_in,
                              void* d_out, int out_size, void* d_ws, size_t ws_size,
                              hipStream_t stream) {
    const float* x       = (const float*)d_in[0];
    const int*   src     = (const int*)d_in[1];
    const int*   dst     = (const int*)d_in[2];
    const float* Wself1  = (const float*)d_in[3];
    const float* Wneigh1 = (const float*)d_in[4];
    const float* b1      = (const float*)d_in[5];
    const float* Wself2  = (const float*)d_in[6];
    const float* Wneigh2 = (const float*)d_in[7];
    const float* b2      = (const float*)d_in[8];
    float* out = (float*)d_out;

    const int n_nodes = in_sizes[0] / DFEAT;
    const int n_edges = in_sizes[1];
    const int nbuck   = (n_nodes + NPB - 1) >> NPB_SHIFT;   // 782

    // Workspace: gcur[1024] | wf1[8192] | wf2[8192] | packbuf | xb | hb
    int* gcur       = (int*)d_ws;
    bf16_t* wf1     = (bf16_t*)(gcur + 1024);
    bf16_t* wf2     = wf1 + 16 * 64 * 8;
    int* packbuf    = (int*)(wf2 + 16 * 64 * 8);
    bf16_t* xb      = (bf16_t*)(packbuf + (size_t)nbuck * BCAP);
    bf16_t* hb      = xb + (size_t)n_nodes * DFEAT;

    const int n_half = n_nodes * DFEAT / 2;
    const int cb = (n_half + 255) / 256;
    const int ab = (n_edges + ATILE - 1) / ATILE;

    hipMemsetAsync(gcur, 0, 1024 * sizeof(int), stream);
    prep_all<<<ab + cb + 1, 256, 0, stream>>>(src, dst, gcur, packbuf, n_edges, nbuck,
                                              x, xb, n_half,
                                              Wself1, Wneigh1, Wself2, Wneigh2,
                                              wf1, wf2, ab, cb);

    fused_layer<<<nbuck, 256, 0, stream>>>(xb, gcur, packbuf, wf1, b1,
                                           nullptr, hb, n_nodes, 1);
    fused_layer<<<nbuck, 256, 0, stream>>>(hb, gcur, packbuf, wf2, b2,
                                           out, nullptr, n_nodes, 0);
}